// Round 6
// baseline (272.887 us; speedup 1.0000x reference)
//
#include <hip/hip_runtime.h>

#define TT 2048
#define BLOCK 256
#define WAVES 4            // rows per block, one per wave

#define LOG2E 1.4426950408889634f

__device__ __forceinline__ float sig_e2(float u) {
    // caller passes u = -x * log2e ; returns 1/(1+2^u) = sigmoid(x)
    return __builtin_amdgcn_rcpf(1.0f + __builtin_amdgcn_exp2f(u));
}

// --------------------------------------------------------------------------
// Kernel 1: scores = sigmoid(logits) (exported once per batch) and
// per-row inverse softmax denominators inv[b][i]. Pure compute, ~256 KB out.
// --------------------------------------------------------------------------
__global__ __launch_bounds__(BLOCK) void prep_kernel(
    const float* __restrict__ logits, const int* __restrict__ seq_len,
    float* __restrict__ ws_scores,   // [B*TT]
    float* __restrict__ ws_inv)      // [B*TT]
{
    __shared__ float s_sc[TT];

    const int b    = blockIdx.y;
    const int row0 = blockIdx.x * WAVES;
    const int tid  = threadIdx.x;
    const int lane = tid & 63;
    const int wv   = tid >> 6;
    const int L    = seq_len[b];     // [1, TT], block-uniform

    // stage sigmoid(logits[b,:]) into LDS (unconditional: logits fully valid)
    const float4* lg4 = (const float4*)(logits + (size_t)b * TT);
    float4* s4 = (float4*)s_sc;
    #pragma unroll
    for (int k = 0; k < 2; ++k) {
        int idx4 = tid + k * BLOCK;
        float4 v = lg4[idx4];
        float4 s;
        s.x = sig_e2(-LOG2E * v.x);
        s.y = sig_e2(-LOG2E * v.y);
        s.z = sig_e2(-LOG2E * v.z);
        s.w = sig_e2(-LOG2E * v.w);
        s4[idx4] = s;
        if (blockIdx.x == 0)   // one block per batch exports the scores row
            ((float4*)(ws_scores + (size_t)b * TT))[idx4] = s;
    }
    __syncthreads();

    const int i = row0 + wv;
    if (i >= L) return;              // invalid rows need no denominator

    const float si = s_sc[i];
    float partial = 0.f;
    #pragma unroll
    for (int q = 0; q < 8; ++q) {
        if (q * 256 < L) {           // wave-uniform (SGPR compare), static q
            const int idx4 = q * 64 + lane;
            float4 sj = s4[idx4];
            const int j0 = idx4 * 4;
            const bool fullgrp = ((q + 1) * 256 <= L);
            float vals[4] = {sj.x, sj.y, sj.z, sj.w};
            #pragma unroll
            for (int qq = 0; qq < 4; ++qq) {
                float d  = si - vals[qq];
                float u  = fmaf(fabsf(d), 10.0f * LOG2E, -5.0f * LOG2E);
                float p  = sig_e2(u);                         // sigmoid((0.5-|d|)/0.1)
                float ee = __builtin_amdgcn_exp2f(p * LOG2E); // exp(p) in (1,e)
                if (!fullgrp)
                    ee = (j0 + qq < L) ? ee : 0.0f;
                partial += ee;
            }
        }
    }
    #pragma unroll
    for (int off = 32; off > 0; off >>= 1)
        partial += __shfl_xor(partial, off, 64);
    if (lane == 0)
        ws_inv[(size_t)b * TT + i] = __builtin_amdgcn_rcpf(partial);
}

// --------------------------------------------------------------------------
// Kernel 2: recompute ee per group, multiply by preloaded inv, store each
// float4 group IMMEDIATELY. No live accumulator array, no reduction ->
// low VGPR, continuous store issue.
// --------------------------------------------------------------------------
__global__ __launch_bounds__(BLOCK) void emit_kernel(
    const int* __restrict__ seq_len,
    const float* __restrict__ ws_scores, const float* __restrict__ ws_inv,
    float* __restrict__ out)
{
    __shared__ float s_sc[TT];

    const int b    = blockIdx.y;
    const int row0 = blockIdx.x * WAVES;
    const int tid  = threadIdx.x;
    const int lane = tid & 63;
    const int wv   = tid >> 6;
    const int L    = seq_len[b];

    const int i = row0 + wv;
    float4* orow4 = (float4*)(out + ((size_t)b * TT + (size_t)i) * TT);
    const float4 z4 = make_float4(0.f, 0.f, 0.f, 0.f);

    // fully-invalid block: stream zeros, no staging, no barrier
    if (row0 >= L) {
        #pragma unroll
        for (int q = 0; q < 8; ++q)
            orow4[q * 64 + lane] = z4;
        return;
    }

    // stage precomputed scores (no sigmoid here)
    const float4* sc4 = (const float4*)(ws_scores + (size_t)b * TT);
    float4* s4 = (float4*)s_sc;
    #pragma unroll
    for (int k = 0; k < 2; ++k) {
        int idx4 = tid + k * BLOCK;
        s4[idx4] = sc4[idx4];
    }
    __syncthreads();

    if (i >= L) {                    // invalid row in mixed block
        #pragma unroll
        for (int q = 0; q < 8; ++q)
            orow4[q * 64 + lane] = z4;
        return;
    }

    // masked column groups -> zeros up front (wave-uniform)
    #pragma unroll
    for (int q = 0; q < 8; ++q)
        if (q * 256 >= L)
            orow4[q * 64 + lane] = z4;

    const float si  = s_sc[i];
    const float inv = ws_inv[(size_t)b * TT + i];   // uniform addr -> broadcast

    #pragma unroll
    for (int q = 0; q < 8; ++q) {
        if (q * 256 < L) {
            const int idx4 = q * 64 + lane;
            float4 sj = s4[idx4];
            const int j0 = idx4 * 4;
            const bool fullgrp = ((q + 1) * 256 <= L);
            float vals[4] = {sj.x, sj.y, sj.z, sj.w};
            float4 o;
            float* ov = (float*)&o;
            #pragma unroll
            for (int qq = 0; qq < 4; ++qq) {
                float d  = si - vals[qq];
                float u  = fmaf(fabsf(d), 10.0f * LOG2E, -5.0f * LOG2E);
                float p  = sig_e2(u);
                float ee = __builtin_amdgcn_exp2f(p * LOG2E);
                if (!fullgrp)
                    ee = (j0 + qq < L) ? ee : 0.0f;
                ov[qq] = ee * inv;
            }
            orow4[idx4] = o;         // store this group NOW
        }
    }
}

// --------------------------------------------------------------------------
// Fallback single-kernel path (round-0 structure) if workspace is too small.
// --------------------------------------------------------------------------
__global__ __launch_bounds__(BLOCK) void score_branch_kernel(
    const float* __restrict__ logits, const int* __restrict__ seq_len,
    float* __restrict__ out)
{
    __shared__ float s_scores[TT];
    const int b    = blockIdx.y;
    const int row0 = blockIdx.x * WAVES;
    const int tid  = threadIdx.x;
    const int lane = tid & 63;
    const int wv   = tid >> 6;
    const int L    = seq_len[b];
    const int i = row0 + wv;
    float4* orow4 = (float4*)(out + ((size_t)b * TT + (size_t)i) * TT);
    const float4 z4 = make_float4(0.f, 0.f, 0.f, 0.f);

    if (row0 >= L) {
        #pragma unroll
        for (int q = 0; q < 8; ++q) orow4[q * 64 + lane] = z4;
        return;
    }
    const float4* lg4 = (const float4*)(logits + (size_t)b * TT);
    float4* s4 = (float4*)s_scores;
    #pragma unroll
    for (int k = 0; k < 2; ++k) {
        int idx4 = tid + k * BLOCK;
        float4 v = lg4[idx4];
        float4 s;
        s.x = sig_e2(-LOG2E * v.x);
        s.y = sig_e2(-LOG2E * v.y);
        s.z = sig_e2(-LOG2E * v.z);
        s.w = sig_e2(-LOG2E * v.w);
        s4[idx4] = s;
    }
    __syncthreads();
    if (i >= L) {
        #pragma unroll
        for (int q = 0; q < 8; ++q) orow4[q * 64 + lane] = z4;
        return;
    }
    const float si = s_scores[i];
    float4 e4[8];
    float partial = 0.f;
    #pragma unroll
    for (int q = 0; q < 8; ++q) {
        if (q * 256 < L) {
            const int idx4 = q * 64 + lane;
            float4 sj = s4[idx4];
            const int j0 = idx4 * 4;
            const bool fullgrp = ((q + 1) * 256 <= L);
            float vals[4] = {sj.x, sj.y, sj.z, sj.w};
            float* ev = (float*)&e4[q];
            #pragma unroll
            for (int qq = 0; qq < 4; ++qq) {
                float d  = si - vals[qq];
                float u  = fmaf(fabsf(d), 10.0f * LOG2E, -5.0f * LOG2E);
                float p  = sig_e2(u);
                float ee = __builtin_amdgcn_exp2f(p * LOG2E);
                if (!fullgrp) ee = (j0 + qq < L) ? ee : 0.0f;
                ev[qq] = ee;
                partial += ee;
            }
        } else {
            orow4[q * 64 + lane] = z4;
        }
    }
    #pragma unroll
    for (int off = 32; off > 0; off >>= 1)
        partial += __shfl_xor(partial, off, 64);
    const float inv = __builtin_amdgcn_rcpf(partial);
    #pragma unroll
    for (int q = 0; q < 8; ++q) {
        if (q * 256 < L) {
            float4 o;
            o.x = e4[q].x * inv; o.y = e4[q].y * inv;
            o.z = e4[q].z * inv; o.w = e4[q].w * inv;
            orow4[q * 64 + lane] = o;
        }
    }
}

extern "C" void kernel_launch(void* const* d_in, const int* in_sizes, int n_in,
                              void* d_out, int out_size, void* d_ws, size_t ws_size,
                              hipStream_t stream) {
    const float* logits  = (const float*)d_in[0];   // [B, T, 1] fp32
    const int*   seq_len = (const int*)d_in[1];     // [B] int32
    float*       out     = (float*)d_out;           // [B, T, T] fp32

    const int B = in_sizes[1];                      // 16
    dim3 grid(TT / WAVES, B), blk(BLOCK);

    const size_t need = (size_t)2 * B * TT * sizeof(float);   // 256 KB
    if (d_ws != nullptr && ws_size >= need) {
        float* ws_scores = (float*)d_ws;
        float* ws_inv    = ws_scores + (size_t)B * TT;
        prep_kernel<<<grid, blk, 0, stream>>>(logits, seq_len, ws_scores, ws_inv);
        emit_kernel<<<grid, blk, 0, stream>>>(seq_len, ws_scores, ws_inv, out);
    } else {
        score_branch_kernel<<<grid, blk, 0, stream>>>(logits, seq_len, out);
    }
}

// Round 12
// 256.721 us; speedup vs baseline: 1.0630x; 1.0630x over previous
//
#include <hip/hip_runtime.h>

#define TT 2048
#define BLOCK 256
#define WAVES 4                       // waves per block
#define RPW 8                         // rows per wave
#define ROWS_PER_BLOCK (WAVES * RPW)  // 32 rows per block

#define LOG2E 1.4426950408889634f

__device__ __forceinline__ float sig_e2(float u) {
    // caller passes u = -x * log2e ; returns 1/(1+2^u) = sigmoid(x)
    return __builtin_amdgcn_rcpf(1.0f + __builtin_amdgcn_exp2f(u));
}

// One block = 32 consecutive rows of one batch. Scores staged in LDS ONCE,
// then each wave sweeps 8 contiguous rows with no further barriers: the
// stores of row r stay in flight while row r+1's compute issues ->
// continuous store stream per wave (fill-like), amortized wave lifecycle.
__global__ __launch_bounds__(BLOCK) void score_branch_kernel(
    const float* __restrict__ logits, const int* __restrict__ seq_len,
    float* __restrict__ out)
{
    __shared__ float s_sc[TT];

    const int b    = blockIdx.y;
    const int row0 = blockIdx.x * ROWS_PER_BLOCK;
    const int tid  = threadIdx.x;
    const int lane = tid & 63;
    const int wv   = tid >> 6;
    const int L    = seq_len[b];      // [1, TT], block-uniform (SGPR)

    const int wrow0 = row0 + wv * RPW;          // this wave's first row
    const float4 z4 = make_float4(0.f, 0.f, 0.f, 0.f);

    // ---- fully-invalid block: stream zeros, no staging, no barrier ----
    if (row0 >= L) {                  // block-uniform
        float4* o4 = (float4*)(out + ((size_t)b * TT + wrow0) * TT);
        for (int r = 0; r < RPW; ++r) {
            #pragma unroll
            for (int q = 0; q < 8; ++q)
                o4[r * (TT / 4) + q * 64 + lane] = z4;
        }
        return;
    }

    // ---- stage scores = sigmoid(logits[b,:]) into LDS, once per block ----
    const float4* lg4 = (const float4*)(logits + (size_t)b * TT);
    float4* s4 = (float4*)s_sc;
    #pragma unroll
    for (int k = 0; k < 2; ++k) {
        int idx4 = tid + k * BLOCK;
        float4 v = lg4[idx4];
        float4 s;
        s.x = sig_e2(-LOG2E * v.x);
        s.y = sig_e2(-LOG2E * v.y);
        s.z = sig_e2(-LOG2E * v.z);
        s.w = sig_e2(-LOG2E * v.w);
        s4[idx4] = s;
    }
    __syncthreads();                  // the ONLY barrier

    // ---- 8-row sweep per wave ----
    for (int r = 0; r < RPW; ++r) {
        const int i = wrow0 + r;
        float4* orow4 = (float4*)(out + ((size_t)b * TT + (size_t)i) * TT);

        if (i >= L) {                 // invalid row: zeros (wave-uniform)
            #pragma unroll
            for (int q = 0; q < 8; ++q)
                orow4[q * 64 + lane] = z4;
            continue;
        }

        const float si = s_sc[i];
        float4 e4[8];
        float partial = 0.f;
        #pragma unroll
        for (int q = 0; q < 8; ++q) {
            if (q * 256 < L) {        // wave-uniform, static q
                const int idx4 = q * 64 + lane;
                float4 sj = s4[idx4];
                const int j0 = idx4 * 4;
                const bool fullgrp = ((q + 1) * 256 <= L);
                float vals[4] = {sj.x, sj.y, sj.z, sj.w};
                float* ev = (float*)&e4[q];
                #pragma unroll
                for (int qq = 0; qq < 4; ++qq) {
                    float d  = si - vals[qq];
                    // t=(0.5-|d|)/0.1 ; u=-t*log2e folded into one fma
                    float u  = fmaf(fabsf(d), 10.0f * LOG2E, -5.0f * LOG2E);
                    float p  = sig_e2(u);                          // in (0,1)
                    float ee = __builtin_amdgcn_exp2f(p * LOG2E);  // exp(p)
                    if (!fullgrp)
                        ee = (j0 + qq < L) ? ee : 0.0f;            // mask -> 0
                    ev[qq] = ee;
                    partial += ee;
                }
            } else {
                orow4[q * 64 + lane] = z4;   // masked group: store zeros now
            }
        }

        // wave-private butterfly reduction — no LDS traffic conflicts, no barrier
        #pragma unroll
        for (int off = 32; off > 0; off >>= 1)
            partial += __shfl_xor(partial, off, 64);
        const float inv = __builtin_amdgcn_rcpf(partial);  // denom > 2.6

        #pragma unroll
        for (int q = 0; q < 8; ++q) {
            if (q * 256 < L) {
                float4 o;
                o.x = e4[q].x * inv;
                o.y = e4[q].y * inv;
                o.z = e4[q].z * inv;
                o.w = e4[q].w * inv;
                orow4[q * 64 + lane] = o;    // in flight across next row's compute
            }
        }
    }
}

extern "C" void kernel_launch(void* const* d_in, const int* in_sizes, int n_in,
                              void* d_out, int out_size, void* d_ws, size_t ws_size,
                              hipStream_t stream) {
    const float* logits  = (const float*)d_in[0];   // [B, T, 1] fp32
    const int*   seq_len = (const int*)d_in[1];     // [B] int32
    float*       out     = (float*)d_out;           // [B, T, T] fp32

    const int B = in_sizes[1];                      // 16
    dim3 grid(TT / ROWS_PER_BLOCK, B);              // (64, 16) = 1024 blocks
    score_branch_kernel<<<grid, dim3(BLOCK), 0, stream>>>(logits, seq_len, out);
}